// Round 4
// baseline (117.166 us; speedup 1.0000x reference)
//
#include <hip/hip_runtime.h>
#include <math.h>

#define CC 256
#define KK 16
#define DD 256
#define NN 4096
#define EPSV 1e-6f

typedef unsigned long long u64;
typedef __attribute__((ext_vector_type(8))) short short8v;
typedef __attribute__((ext_vector_type(8))) unsigned short ushort8v;
typedef __attribute__((ext_vector_type(4))) float f32x4;

// ---------------- kernel 0: fused prep ----------------
// Block g handles rows 16g..16g+15: computes sq norms, inits mining keys,
// splits fp32 -> (hi,lo) bf16 and stores in MFMA-fragment order.
// Fragment layout for mfma_f32_16x16x32_bf16 (A and B coincide for Gram):
//   lane l of fragment (rowgroup g, kslice s) holds
//   E[16g + (l&15)][32s + (l>>4)*8 .. +7]   flat: frag[((g*8+s)*64+l)*8 + e]
__global__ __launch_bounds__(256) void prep_kernel(const float* __restrict__ emb,
                                                   float* __restrict__ sq,
                                                   unsigned short* __restrict__ hi,
                                                   unsigned short* __restrict__ lo,
                                                   u64* __restrict__ posk,
                                                   u64* __restrict__ negk,
                                                   float* __restrict__ out) {
  __shared__ __attribute__((aligned(16))) unsigned short hiS[16][264];
  __shared__ __attribute__((aligned(16))) unsigned short loS[16][264];
  const int g = blockIdx.x;  // 0..255
  const int t = threadIdx.x;
  const int r = t >> 4, q = t & 15;
  const int row = g * 16 + r;

  const float* src = emb + (size_t)row * DD + q * 16;
  float s = 0.f;
  #pragma unroll
  for (int i = 0; i < 4; ++i) {
    float4 v = *reinterpret_cast<const float4*>(src + 4 * i);
    float f[4] = {v.x, v.y, v.z, v.w};
    #pragma unroll
    for (int e = 0; e < 4; ++e) {
      s += f[e] * f[e];
      unsigned b = __float_as_uint(f[e]);
      hiS[r][q * 16 + 4 * i + e] = (unsigned short)(b >> 16);          // truncate
      float fl = f[e] - __uint_as_float(b & 0xFFFF0000u);              // residual
      loS[r][q * 16 + 4 * i + e] = (unsigned short)(__float_as_uint(fl) >> 16);
    }
  }
  // row sqnorm: reduce across the 16 lanes of this row (lane = (r&3)*16+q)
  #pragma unroll
  for (int off = 1; off < 16; off <<= 1) s += __shfl_xor(s, off);
  if (q == 0) {
    sq[row] = s;
    posk[row] = 0ull;   // max-key init
    negk[row] = ~0ull;  // min-key init
  }
  if (g == 0 && t == 0) out[0] = 0.0f;
  __syncthreads();

  // write fragment-ordered, 2 chunks per thread per array (coalesced 16B)
  #pragma unroll
  for (int h = 0; h < 2; ++h) {
    int q2 = h * 256 + t;  // 0..511
    int s2 = q2 >> 6, fl = q2 & 63;
    int col = 32 * s2 + 8 * (fl >> 4);
    ushort8v hv = *reinterpret_cast<const ushort8v*>(&hiS[fl & 15][col]);
    ushort8v lv = *reinterpret_cast<const ushort8v*>(&loS[fl & 15][col]);
    size_t o = ((size_t)(g * 8 + s2) * 64 + fl) * 8;
    __builtin_nontemporal_store(hv, reinterpret_cast<ushort8v*>(hi + o));
    __builtin_nontemporal_store(lv, reinterpret_cast<ushort8v*>(lo + o));
  }
}

// ---------------- kernel 1: MFMA gram-tile mining, triangular grid ----------
// 528 blocks = upper triangle of 32x32 tiles of 128x128. 4 waves = 2x2 of 64x64.
// Depth-1 register double-buffer: loads of slice s+1 issue before MFMAs of s.
#define LOAD_SET(dahi, dalo, dbhi, dblo, S)                                    \
  {                                                                            \
    const int so = (S) * 512;                                                  \
    _Pragma("unroll") for (int m = 0; m < 4; ++m) {                            \
      dahi[m] = *reinterpret_cast<const short8v*>(hi + ofsA[m] + so);          \
      dalo[m] = *reinterpret_cast<const short8v*>(lo + ofsA[m] + so);          \
    }                                                                          \
    _Pragma("unroll") for (int n = 0; n < 4; ++n) {                            \
      dbhi[n] = *reinterpret_cast<const short8v*>(hi + ofsB[n] + so);          \
      dblo[n] = *reinterpret_cast<const short8v*>(lo + ofsB[n] + so);          \
    }                                                                          \
  }

#define MFMA_SET(ahi, alo, bhi, blo)                                           \
  {                                                                            \
    _Pragma("unroll") for (int m = 0; m < 4; ++m)                              \
        _Pragma("unroll") for (int n = 0; n < 4; ++n) {                        \
      acc[m][n] = __builtin_amdgcn_mfma_f32_16x16x32_bf16(ahi[m], bhi[n],      \
                                                          acc[m][n], 0, 0, 0); \
      acc[m][n] = __builtin_amdgcn_mfma_f32_16x16x32_bf16(ahi[m], blo[n],      \
                                                          acc[m][n], 0, 0, 0); \
      acc[m][n] = __builtin_amdgcn_mfma_f32_16x16x32_bf16(alo[m], bhi[n],      \
                                                          acc[m][n], 0, 0, 0); \
    }                                                                          \
  }

__global__ __launch_bounds__(256, 2) void mine_mfma_kernel(const unsigned short* __restrict__ hi,
                                                           const unsigned short* __restrict__ lo,
                                                           const float* __restrict__ sq,
                                                           u64* __restrict__ posk,
                                                           u64* __restrict__ negk) {
  // unrank upper-triangular tile index
  int rem = blockIdx.x;
  int ib = 0;
  #pragma unroll 1
  for (int r = 0; r < 32; ++r) {
    int cnt = 32 - r;
    if (rem < cnt) { ib = r; break; }
    rem -= cnt;
  }
  const int jb = ib + rem;
  const bool diag = (ib == jb);
  const int ibRow = ib * 128, jbRow = jb * 128;

  const int tid = threadIdx.x;
  const int lane = tid & 63;
  const int w = tid >> 6;
  const int wm = w >> 1, wn = w & 1;
  const int fr = lane & 15;
  const int grp = lane >> 4;

  int ofsA[4], ofsB[4];
  #pragma unroll
  for (int m = 0; m < 4; ++m) ofsA[m] = (ib * 8 + wm * 4 + m) * 4096 + lane * 8;
  #pragma unroll
  for (int n = 0; n < 4; ++n) ofsB[n] = (jb * 8 + wn * 4 + n) * 4096 + lane * 8;

  f32x4 acc[4][4];
  #pragma unroll
  for (int m = 0; m < 4; ++m)
    #pragma unroll
    for (int n = 0; n < 4; ++n)
      acc[m][n] = (f32x4){0.f, 0.f, 0.f, 0.f};

  short8v pAhi[4], pAlo[4], pBhi[4], pBlo[4];
  short8v qAhi[4], qAlo[4], qBhi[4], qBlo[4];
  LOAD_SET(pAhi, pAlo, pBhi, pBlo, 0);
  #pragma unroll 1
  for (int s = 0; s < 8; s += 2) {
    LOAD_SET(qAhi, qAlo, qBhi, qBlo, s + 1);
    MFMA_SET(pAhi, pAlo, pBhi, pBlo);
    if (s < 6) LOAD_SET(pAhi, pAlo, pBhi, pBlo, s + 2);
    MFMA_SET(qAhi, qAlo, qBhi, qBlo);
  }

  // ---- epilogue on d^2 (sqrt is monotone; ties preserved) ----
  // C layout: col = lane&15, row = (lane>>4)*4 + reg
  float sqjv[4]; int jglob[4];
  #pragma unroll
  for (int n = 0; n < 4; ++n) {
    jglob[n] = jbRow + wn * 64 + n * 16 + fr;
    sqjv[n] = sq[jglob[n]];
  }
  float sqiv[4][4]; int iglob[4][4];
  #pragma unroll
  for (int m = 0; m < 4; ++m)
    #pragma unroll
    for (int r = 0; r < 4; ++r) {
      iglob[m][r] = ibRow + wm * 64 + m * 16 + grp * 4 + r;
      sqiv[m][r] = sq[iglob[m][r]];
    }

  // row scan: rows of ib-group vs cols of jb-group
  #pragma unroll
  for (int m = 0; m < 4; ++m) {
    #pragma unroll
    for (int r = 0; r < 4; ++r) {
      const int gi = iglob[m][r];
      float pv = -1.0f; int pj = -1;
      float nv = 3.0e38f; int nj = 0x7fffffff;
      #pragma unroll
      for (int n = 0; n < 4; ++n) {
        const float d2 = fmaxf(sqiv[m][r] + sqjv[n] - 2.0f * acc[m][n][r], 0.0f);
        const int j = jglob[n];
        const bool isPos = diag && ((j >> 4) == (gi >> 4));
        if (isPos) {
          if (d2 > pv || (d2 == pv && j < pj)) { pv = d2; pj = j; }
        } else {
          if (d2 < nv || (d2 == nv && j < nj)) { nv = d2; nj = j; }
        }
      }
      #pragma unroll
      for (int off = 1; off < 16; off <<= 1) {
        float ov = __shfl_xor(nv, off); int oj = __shfl_xor(nj, off);
        if (ov < nv || (ov == nv && oj < nj)) { nv = ov; nj = oj; }
        float pov = __shfl_xor(pv, off); int poj = __shfl_xor(pj, off);
        if (pov > pv || (pov == pv && ((unsigned)poj < (unsigned)pj))) { pv = pov; pj = poj; }
      }
      if (fr == 0) {
        if (nj != 0x7fffffff)
          atomicMin(&negk[gi], ((u64)__float_as_uint(nv) << 32) | (unsigned)nj);
        if (diag && pj >= 0)
          atomicMax(&posk[gi], ((u64)__float_as_uint(pv) << 32) |
                                   (unsigned)(0xFFFFFFFFu - (unsigned)pj));
      }
    }
  }

  // column scan (transpose side), off-diagonal tiles only: all negatives
  if (!diag) {
    #pragma unroll
    for (int n = 0; n < 4; ++n) {
      float nv = 3.0e38f; int ni = 0x7fffffff;
      #pragma unroll
      for (int m = 0; m < 4; ++m)
        #pragma unroll
        for (int r = 0; r < 4; ++r) {
          const float d2 = fmaxf(sqiv[m][r] + sqjv[n] - 2.0f * acc[m][n][r], 0.0f);
          if (d2 < nv || (d2 == nv && iglob[m][r] < ni)) { nv = d2; ni = iglob[m][r]; }
        }
      #pragma unroll
      for (int off = 16; off < 64; off <<= 1) {
        float ov = __shfl_xor(nv, off); int oi = __shfl_xor(ni, off);
        if (ov < nv || (ov == nv && oi < ni)) { nv = ov; ni = oi; }
      }
      if (grp == 0)
        atomicMin(&negk[jglob[n]], ((u64)__float_as_uint(nv) << 32) | (unsigned)ni);
    }
  }
}

// ---------------- kernel 2: exact fp32 triplet terms + fused mean -----------
// 256 blocks x 1024 threads = 16 waves = 16 rows/block; one atomicAdd/block.
__global__ __launch_bounds__(1024) void triplet_kernel(const float* __restrict__ emb,
                                                       const u64* __restrict__ posk,
                                                       const u64* __restrict__ negk,
                                                       float* __restrict__ out) {
  __shared__ float part[16];
  const int w = threadIdx.x >> 6;
  const int lane = threadIdx.x & 63;
  const int i = blockIdx.x * 16 + w;

  u64 pk = posk[i], nk = negk[i];
  int p = (int)(0xFFFFFFFFu - (unsigned)(pk & 0xFFFFFFFFu));
  int nidx = (int)(nk & 0xFFFFFFFFu);

  float4 e  = *reinterpret_cast<const float4*>(emb + (size_t)i * DD + 4 * lane);
  float4 ep = *reinterpret_cast<const float4*>(emb + (size_t)p * DD + 4 * lane);
  float4 en = *reinterpret_cast<const float4*>(emb + (size_t)nidx * DD + 4 * lane);

  float dpx = e.x - ep.x + EPSV, dpy = e.y - ep.y + EPSV,
        dpz = e.z - ep.z + EPSV, dpw = e.w - ep.w + EPSV;
  float dnx = e.x - en.x + EPSV, dny = e.y - en.y + EPSV,
        dnz = e.z - en.z + EPSV, dnw = e.w - en.w + EPSV;
  float sp = dpx * dpx + dpy * dpy + dpz * dpz + dpw * dpw;
  float sn = dnx * dnx + dny * dny + dnz * dnz + dnw * dnw;
  #pragma unroll
  for (int off = 32; off; off >>= 1) {
    sp += __shfl_xor(sp, off);
    sn += __shfl_xor(sn, off);
  }
  if (lane == 0) part[w] = fmaxf(sqrtf(sp) - sqrtf(sn) + 1.0f, 0.0f);
  __syncthreads();
  if (threadIdx.x == 0) {
    float s = 0.f;
    #pragma unroll
    for (int k = 0; k < 16; ++k) s += part[k];
    atomicAdd(out, s * (1.0f / NN));
  }
}

extern "C" void kernel_launch(void* const* d_in, const int* in_sizes, int n_in,
                              void* d_out, int out_size, void* d_ws, size_t ws_size,
                              hipStream_t stream) {
  const float* emb = (const float*)d_in[0];  // [N, D] row-major
  char* ws = (char*)d_ws;
  float* sq = (float*)ws;                  // 16 KB
  u64* posk = (u64*)(ws + (16 << 10));     // 32 KB
  u64* negk = (u64*)(ws + (48 << 10));     // 32 KB
  unsigned short* hi = (unsigned short*)(ws + (96 << 10));             // 2 MB
  unsigned short* lo = (unsigned short*)(ws + (96 << 10) + (2 << 20)); // 2 MB
  float* out = (float*)d_out;

  prep_kernel<<<256, 256, 0, stream>>>(emb, sq, hi, lo, posk, negk, out);
  mine_mfma_kernel<<<528, 256, 0, stream>>>(hi, lo, sq, posk, negk);
  triplet_kernel<<<256, 1024, 0, stream>>>(emb, posk, negk, out);
}

// Round 5
// 95.799 us; speedup vs baseline: 1.2230x; 1.2230x over previous
//
#include <hip/hip_runtime.h>
#include <math.h>

#define CC 256
#define KK 16
#define DD 256
#define NN 4096
#define EPSV 1e-6f

typedef unsigned long long u64;
typedef __attribute__((ext_vector_type(8))) short short8v;
typedef __attribute__((ext_vector_type(8))) unsigned short ushort8v;
typedef __attribute__((ext_vector_type(4))) float f32x4;

// ---------------- kernel 0: fused prep ----------------
// Block g handles rows 16g..16g+15: sq norms, key init, fp32 -> bf16(hi) in
// MFMA fragment order. Fragment layout (A and B coincide for Gram):
//   lane l of fragment (rowgroup g, kslice s) holds
//   E[16g + (l&15)][32s + (l>>4)*8 .. +7]   flat: frag[((g*8+s)*64+l)*8 + e]
__global__ __launch_bounds__(256) void prep_kernel(const float* __restrict__ emb,
                                                   float* __restrict__ sq,
                                                   unsigned short* __restrict__ hi,
                                                   u64* __restrict__ posk,
                                                   u64* __restrict__ negk,
                                                   float* __restrict__ out) {
  __shared__ __attribute__((aligned(16))) unsigned short hiS[16][264];
  const int g = blockIdx.x;  // 0..255
  const int t = threadIdx.x;
  const int r = t >> 4, q = t & 15;
  const int row = g * 16 + r;

  const float* src = emb + (size_t)row * DD + q * 16;
  float s = 0.f;
  #pragma unroll
  for (int i = 0; i < 4; ++i) {
    float4 v = *reinterpret_cast<const float4*>(src + 4 * i);
    float f[4] = {v.x, v.y, v.z, v.w};
    #pragma unroll
    for (int e = 0; e < 4; ++e) {
      s += f[e] * f[e];
      hiS[r][q * 16 + 4 * i + e] = (unsigned short)(__float_as_uint(f[e]) >> 16);
    }
  }
  // row sqnorm: reduce across the 16 lanes of this row
  #pragma unroll
  for (int off = 1; off < 16; off <<= 1) s += __shfl_xor(s, off);
  if (q == 0) {
    sq[row] = s;
    posk[row] = 0ull;   // max-key init
    negk[row] = ~0ull;  // min-key init
  }
  if (g == 0 && t == 0) out[0] = 0.0f;
  __syncthreads();

  // write fragment-ordered, 2 chunks per thread (coalesced 16B)
  #pragma unroll
  for (int h = 0; h < 2; ++h) {
    int q2 = h * 256 + t;  // 0..511
    int s2 = q2 >> 6, fl = q2 & 63;
    int col = 32 * s2 + 8 * (fl >> 4);
    ushort8v hv = *reinterpret_cast<const ushort8v*>(&hiS[fl & 15][col]);
    *reinterpret_cast<ushort8v*>(hi + ((size_t)(g * 8 + s2) * 64 + fl) * 8) = hv;
  }
}

// ---------------- kernel 1: MFMA gram-tile mining, full square grid --------
// 1024 blocks = 32x32 tiles of 128x128. 4 waves = 2x2 of 64x64 sub-tiles.
// hi-only (bf16 truncation): ranking-accurate; exact recompute follows.
__global__ __launch_bounds__(256, 4) void mine_mfma_kernel(const unsigned short* __restrict__ hi,
                                                           const float* __restrict__ sq,
                                                           u64* __restrict__ posk,
                                                           u64* __restrict__ negk) {
  const int ib = blockIdx.x >> 5, jb = blockIdx.x & 31;
  const bool diag = (ib == jb);
  const int ibRow = ib * 128, jbRow = jb * 128;

  const int tid = threadIdx.x;
  const int lane = tid & 63;
  const int w = tid >> 6;
  const int wm = w >> 1, wn = w & 1;
  const int fr = lane & 15;
  const int grp = lane >> 4;

  int ofsA[4], ofsB[4];
  #pragma unroll
  for (int m = 0; m < 4; ++m) ofsA[m] = (ib * 8 + wm * 4 + m) * 4096 + lane * 8;
  #pragma unroll
  for (int n = 0; n < 4; ++n) ofsB[n] = (jb * 8 + wn * 4 + n) * 4096 + lane * 8;

  f32x4 acc[4][4];
  #pragma unroll
  for (int m = 0; m < 4; ++m)
    #pragma unroll
    for (int n = 0; n < 4; ++n)
      acc[m][n] = (f32x4){0.f, 0.f, 0.f, 0.f};

  #pragma unroll 2
  for (int s = 0; s < 8; ++s) {
    short8v a[4], b[4];
    #pragma unroll
    for (int m = 0; m < 4; ++m)
      a[m] = *reinterpret_cast<const short8v*>(hi + ofsA[m] + s * 512);
    #pragma unroll
    for (int n = 0; n < 4; ++n)
      b[n] = *reinterpret_cast<const short8v*>(hi + ofsB[n] + s * 512);
    #pragma unroll
    for (int m = 0; m < 4; ++m)
      #pragma unroll
      for (int n = 0; n < 4; ++n)
        acc[m][n] = __builtin_amdgcn_mfma_f32_16x16x32_bf16(a[m], b[n], acc[m][n], 0, 0, 0);
  }

  // ---- epilogue on d^2 (sqrt monotone; ranking only — exact recompute later)
  // C layout: col = lane&15, row = (lane>>4)*4 + reg
  float sqjv[4]; int jglob[4];
  #pragma unroll
  for (int n = 0; n < 4; ++n) {
    jglob[n] = jbRow + wn * 64 + n * 16 + fr;
    sqjv[n] = sq[jglob[n]];
  }

  #pragma unroll
  for (int m = 0; m < 4; ++m) {
    #pragma unroll
    for (int r = 0; r < 4; ++r) {
      const int gi = ibRow + wm * 64 + m * 16 + grp * 4 + r;
      const float sqiv = sq[gi];
      float pv = -1.0f; int pj = -1;
      float nv = 3.0e38f; int nj = 0x7fffffff;
      #pragma unroll
      for (int n = 0; n < 4; ++n) {
        const float d2 = fmaxf(sqiv + sqjv[n] - 2.0f * acc[m][n][r], 0.0f);
        const int j = jglob[n];
        const bool isPos = diag && ((j >> 4) == (gi >> 4));
        if (isPos) {
          if (d2 > pv || (d2 == pv && j < pj)) { pv = d2; pj = j; }
        } else {
          if (d2 < nv || (d2 == nv && j < nj)) { nv = d2; nj = j; }
        }
      }
      #pragma unroll
      for (int off = 1; off < 16; off <<= 1) {
        float ov = __shfl_xor(nv, off); int oj = __shfl_xor(nj, off);
        if (ov < nv || (ov == nv && oj < nj)) { nv = ov; nj = oj; }
        float pov = __shfl_xor(pv, off); int poj = __shfl_xor(pj, off);
        if (pov > pv || (pov == pv && ((unsigned)poj < (unsigned)pj))) { pv = pov; pj = poj; }
      }
      if (fr == 0) {
        if (nj != 0x7fffffff)
          atomicMin(&negk[gi], ((u64)__float_as_uint(nv) << 32) | (unsigned)nj);
        if (diag && pj >= 0)
          atomicMax(&posk[gi], ((u64)__float_as_uint(pv) << 32) |
                                   (unsigned)(0xFFFFFFFFu - (unsigned)pj));
      }
    }
  }
}

// ---------------- kernel 2: exact fp32 triplet terms + fused mean -----------
// 256 blocks x 1024 threads = 16 waves = 16 rows/block; one atomicAdd/block.
__global__ __launch_bounds__(1024) void triplet_kernel(const float* __restrict__ emb,
                                                       const u64* __restrict__ posk,
                                                       const u64* __restrict__ negk,
                                                       float* __restrict__ out) {
  __shared__ float part[16];
  const int w = threadIdx.x >> 6;
  const int lane = threadIdx.x & 63;
  const int i = blockIdx.x * 16 + w;

  u64 pk = posk[i], nk = negk[i];
  int p = (int)(0xFFFFFFFFu - (unsigned)(pk & 0xFFFFFFFFu));
  int nidx = (int)(nk & 0xFFFFFFFFu);

  float4 e  = *reinterpret_cast<const float4*>(emb + (size_t)i * DD + 4 * lane);
  float4 ep = *reinterpret_cast<const float4*>(emb + (size_t)p * DD + 4 * lane);
  float4 en = *reinterpret_cast<const float4*>(emb + (size_t)nidx * DD + 4 * lane);

  float dpx = e.x - ep.x + EPSV, dpy = e.y - ep.y + EPSV,
        dpz = e.z - ep.z + EPSV, dpw = e.w - ep.w + EPSV;
  float dnx = e.x - en.x + EPSV, dny = e.y - en.y + EPSV,
        dnz = e.z - en.z + EPSV, dnw = e.w - en.w + EPSV;
  float sp = dpx * dpx + dpy * dpy + dpz * dpz + dpw * dpw;
  float sn = dnx * dnx + dny * dny + dnz * dnz + dnw * dnw;
  #pragma unroll
  for (int off = 32; off; off >>= 1) {
    sp += __shfl_xor(sp, off);
    sn += __shfl_xor(sn, off);
  }
  if (lane == 0) part[w] = fmaxf(sqrtf(sp) - sqrtf(sn) + 1.0f, 0.0f);
  __syncthreads();
  if (threadIdx.x == 0) {
    float s = 0.f;
    #pragma unroll
    for (int k = 0; k < 16; ++k) s += part[k];
    atomicAdd(out, s * (1.0f / NN));
  }
}

extern "C" void kernel_launch(void* const* d_in, const int* in_sizes, int n_in,
                              void* d_out, int out_size, void* d_ws, size_t ws_size,
                              hipStream_t stream) {
  const float* emb = (const float*)d_in[0];  // [N, D] row-major
  char* ws = (char*)d_ws;
  float* sq = (float*)ws;                  // 16 KB
  u64* posk = (u64*)(ws + (16 << 10));     // 32 KB
  u64* negk = (u64*)(ws + (48 << 10));     // 32 KB
  unsigned short* hi = (unsigned short*)(ws + (96 << 10));  // 2 MB
  float* out = (float*)d_out;

  prep_kernel<<<256, 256, 0, stream>>>(emb, sq, hi, posk, negk, out);
  mine_mfma_kernel<<<1024, 256, 0, stream>>>(hi, sq, posk, negk);
  triplet_kernel<<<256, 1024, 0, stream>>>(emb, posk, negk, out);
}

// Round 6
// 92.264 us; speedup vs baseline: 1.2699x; 1.0383x over previous
//
#include <hip/hip_runtime.h>
#include <math.h>

#define CC 256
#define KK 16
#define DD 256
#define NN 4096
#define EPSV 1e-6f

typedef unsigned long long u64;
typedef __attribute__((ext_vector_type(8))) short short8v;
typedef __attribute__((ext_vector_type(8))) unsigned short ushort8v;
typedef __attribute__((ext_vector_type(4))) float f32x4;

// ---------------- kernel 0: fused prep ----------------
// Block g handles rows 16g..16g+15: sq norms, key init, fp32 -> bf16(hi) in
// MFMA fragment order. Fragment layout (A and B coincide for Gram):
//   lane l of fragment (rowgroup g, kslice s) holds
//   E[16g + (l&15)][32s + (l>>4)*8 .. +7]   flat: frag[((g*8+s)*64+l)*8 + e]
__global__ __launch_bounds__(256) void prep_kernel(const float* __restrict__ emb,
                                                   float* __restrict__ sq,
                                                   unsigned short* __restrict__ hi,
                                                   u64* __restrict__ posk,
                                                   u64* __restrict__ negk,
                                                   float* __restrict__ out) {
  __shared__ __attribute__((aligned(16))) unsigned short hiS[16][264];
  const int g = blockIdx.x;  // 0..255
  const int t = threadIdx.x;
  const int r = t >> 4, q = t & 15;
  const int row = g * 16 + r;

  const float* src = emb + (size_t)row * DD + q * 16;
  float s = 0.f;
  #pragma unroll
  for (int i = 0; i < 4; ++i) {
    float4 v = *reinterpret_cast<const float4*>(src + 4 * i);
    float f[4] = {v.x, v.y, v.z, v.w};
    #pragma unroll
    for (int e = 0; e < 4; ++e) {
      s += f[e] * f[e];
      hiS[r][q * 16 + 4 * i + e] = (unsigned short)(__float_as_uint(f[e]) >> 16);
    }
  }
  // row sqnorm: reduce across the 16 lanes of this row
  #pragma unroll
  for (int off = 1; off < 16; off <<= 1) s += __shfl_xor(s, off);
  if (q == 0) {
    sq[row] = s;
    posk[row] = 0ull;   // max-key init
    negk[row] = ~0ull;  // min-key init
  }
  if (g == 0 && t == 0) out[0] = 0.0f;
  __syncthreads();

  // write fragment-ordered, 2 chunks per thread (coalesced 16B)
  #pragma unroll
  for (int h = 0; h < 2; ++h) {
    int q2 = h * 256 + t;  // 0..511
    int s2 = q2 >> 6, fl = q2 & 63;
    int col = 32 * s2 + 8 * (fl >> 4);
    ushort8v hv = *reinterpret_cast<const ushort8v*>(&hiS[fl & 15][col]);
    *reinterpret_cast<ushort8v*>(hi + ((size_t)(g * 8 + s2) * 64 + fl) * 8) = hv;
  }
}

// async 16B global->LDS copy (per-lane global addr, wave-uniform LDS base)
__device__ __forceinline__ void gll16(const unsigned short* g, unsigned short* l) {
  __builtin_amdgcn_global_load_lds(
      (const __attribute__((address_space(1))) unsigned int*)(const void*)g,
      (__attribute__((address_space(3))) unsigned int*)(void*)l, 16, 0, 0);
}

// ---------------- kernel 1: MFMA gram-tile mining, LDS 2-phase pipeline ----
// 1024 blocks = 32x32 tiles of 128x128. 4 waves = 2x2 of 64x64 sub-tiles.
// hi-only bf16 mining (ranking); exact fp32 recompute in triplet_kernel.
// Per k-slice: block stages 16KB (8 A-chunks + 8 B-chunks of 1KB, wave-linear)
// into double-buffered LDS via global_load_lds; stage(s+1) issued before
// compute(s); single __syncthreads per slice (its vmcnt drain = the wait).
__global__ __launch_bounds__(256, 4) void mine_mfma_kernel(const unsigned short* __restrict__ hi,
                                                           const float* __restrict__ sq,
                                                           u64* __restrict__ posk,
                                                           u64* __restrict__ negk) {
  __shared__ __attribute__((aligned(16))) unsigned short lds[2][8192];  // 2 x 16KB

  const int ib = blockIdx.x >> 5, jb = blockIdx.x & 31;
  const bool diag = (ib == jb);
  const int ibRow = ib * 128, jbRow = jb * 128;

  const int tid = threadIdx.x;
  const int lane = tid & 63;
  const int w = tid >> 6;
  const int wm = w >> 1, wn = w & 1;
  const int fr = lane & 15;
  const int grp = lane >> 4;

  // chunk (absolute rowgroup G, slice s) lives at hi + (G*8+s)*512 shorts,
  // lane data at +lane*8. Wave w stages chunks {2w, 2w+1} of both A and B.
  const int a0 = 2 * w, a1 = a0 + 1;
  const unsigned short* gA0 = hi + (size_t)(ib * 8 + a0) * 4096 + lane * 8;
  const unsigned short* gA1 = hi + (size_t)(ib * 8 + a1) * 4096 + lane * 8;
  const unsigned short* gB0 = hi + (size_t)(jb * 8 + a0) * 4096 + lane * 8;
  const unsigned short* gB1 = hi + (size_t)(jb * 8 + a1) * 4096 + lane * 8;

  f32x4 acc[4][4];
  #pragma unroll
  for (int m = 0; m < 4; ++m)
    #pragma unroll
    for (int n = 0; n < 4; ++n)
      acc[m][n] = (f32x4){0.f, 0.f, 0.f, 0.f};

  // prologue: stage slice 0 into parity 0
  gll16(gA0, &lds[0][a0 * 512]);
  gll16(gA1, &lds[0][a1 * 512]);
  gll16(gB0, &lds[0][4096 + a0 * 512]);
  gll16(gB1, &lds[0][4096 + a1 * 512]);
  __syncthreads();

  #pragma unroll
  for (int s = 0; s < 8; ++s) {
    const int p = s & 1;
    if (s < 7) {  // issue next-slice staging before compute
      const int so = (s + 1) * 512;
      gll16(gA0 + so, &lds[p ^ 1][a0 * 512]);
      gll16(gA1 + so, &lds[p ^ 1][a1 * 512]);
      gll16(gB0 + so, &lds[p ^ 1][4096 + a0 * 512]);
      gll16(gB1 + so, &lds[p ^ 1][4096 + a1 * 512]);
    }
    short8v a[4], b[4];
    #pragma unroll
    for (int m = 0; m < 4; ++m)
      a[m] = *reinterpret_cast<const short8v*>(&lds[p][(wm * 4 + m) * 512 + lane * 8]);
    #pragma unroll
    for (int n = 0; n < 4; ++n)
      b[n] = *reinterpret_cast<const short8v*>(&lds[p][4096 + (wn * 4 + n) * 512 + lane * 8]);
    #pragma unroll
    for (int m = 0; m < 4; ++m)
      #pragma unroll
      for (int n = 0; n < 4; ++n)
        acc[m][n] = __builtin_amdgcn_mfma_f32_16x16x32_bf16(a[m], b[n], acc[m][n], 0, 0, 0);
    __syncthreads();  // drains vmcnt (next stage done) + lgkmcnt
  }

  // ---- epilogue on d^2 (sqrt monotone; ranking only — exact recompute later)
  // C layout: col = lane&15, row = (lane>>4)*4 + reg
  float sqjv[4]; int jglob[4];
  #pragma unroll
  for (int n = 0; n < 4; ++n) {
    jglob[n] = jbRow + wn * 64 + n * 16 + fr;
    sqjv[n] = sq[jglob[n]];
  }

  #pragma unroll
  for (int m = 0; m < 4; ++m) {
    #pragma unroll
    for (int r = 0; r < 4; ++r) {
      const int gi = ibRow + wm * 64 + m * 16 + grp * 4 + r;
      const float sqiv = sq[gi];
      float pv = -1.0f; int pj = -1;
      float nv = 3.0e38f; int nj = 0x7fffffff;
      #pragma unroll
      for (int n = 0; n < 4; ++n) {
        const float d2 = fmaxf(sqiv + sqjv[n] - 2.0f * acc[m][n][r], 0.0f);
        const int j = jglob[n];
        const bool isPos = diag && ((j >> 4) == (gi >> 4));
        if (isPos) {
          if (d2 > pv || (d2 == pv && j < pj)) { pv = d2; pj = j; }
        } else {
          if (d2 < nv || (d2 == nv && j < nj)) { nv = d2; nj = j; }
        }
      }
      #pragma unroll
      for (int off = 1; off < 16; off <<= 1) {
        float ov = __shfl_xor(nv, off); int oj = __shfl_xor(nj, off);
        if (ov < nv || (ov == nv && oj < nj)) { nv = ov; nj = oj; }
        float pov = __shfl_xor(pv, off); int poj = __shfl_xor(pj, off);
        if (pov > pv || (pov == pv && ((unsigned)poj < (unsigned)pj))) { pv = pov; pj = poj; }
      }
      if (fr == 0) {
        if (nj != 0x7fffffff)
          atomicMin(&negk[gi], ((u64)__float_as_uint(nv) << 32) | (unsigned)nj);
        if (diag && pj >= 0)
          atomicMax(&posk[gi], ((u64)__float_as_uint(pv) << 32) |
                                   (unsigned)(0xFFFFFFFFu - (unsigned)pj));
      }
    }
  }
}

// ---------------- kernel 2: exact fp32 triplet terms + fused mean -----------
// 256 blocks x 1024 threads = 16 waves = 16 rows/block; one atomicAdd/block.
__global__ __launch_bounds__(1024) void triplet_kernel(const float* __restrict__ emb,
                                                       const u64* __restrict__ posk,
                                                       const u64* __restrict__ negk,
                                                       float* __restrict__ out) {
  __shared__ float part[16];
  const int w = threadIdx.x >> 6;
  const int lane = threadIdx.x & 63;
  const int i = blockIdx.x * 16 + w;

  u64 pk = posk[i], nk = negk[i];
  int p = (int)(0xFFFFFFFFu - (unsigned)(pk & 0xFFFFFFFFu));
  int nidx = (int)(nk & 0xFFFFFFFFu);

  float4 e  = *reinterpret_cast<const float4*>(emb + (size_t)i * DD + 4 * lane);
  float4 ep = *reinterpret_cast<const float4*>(emb + (size_t)p * DD + 4 * lane);
  float4 en = *reinterpret_cast<const float4*>(emb + (size_t)nidx * DD + 4 * lane);

  float dpx = e.x - ep.x + EPSV, dpy = e.y - ep.y + EPSV,
        dpz = e.z - ep.z + EPSV, dpw = e.w - ep.w + EPSV;
  float dnx = e.x - en.x + EPSV, dny = e.y - en.y + EPSV,
        dnz = e.z - en.z + EPSV, dnw = e.w - en.w + EPSV;
  float sp = dpx * dpx + dpy * dpy + dpz * dpz + dpw * dpw;
  float sn = dnx * dnx + dny * dny + dnz * dnz + dnw * dnw;
  #pragma unroll
  for (int off = 32; off; off >>= 1) {
    sp += __shfl_xor(sp, off);
    sn += __shfl_xor(sn, off);
  }
  if (lane == 0) part[w] = fmaxf(sqrtf(sp) - sqrtf(sn) + 1.0f, 0.0f);
  __syncthreads();
  if (threadIdx.x == 0) {
    float s = 0.f;
    #pragma unroll
    for (int k = 0; k < 16; ++k) s += part[k];
    atomicAdd(out, s * (1.0f / NN));
  }
}

extern "C" void kernel_launch(void* const* d_in, const int* in_sizes, int n_in,
                              void* d_out, int out_size, void* d_ws, size_t ws_size,
                              hipStream_t stream) {
  const float* emb = (const float*)d_in[0];  // [N, D] row-major
  char* ws = (char*)d_ws;
  float* sq = (float*)ws;                  // 16 KB
  u64* posk = (u64*)(ws + (16 << 10));     // 32 KB
  u64* negk = (u64*)(ws + (48 << 10));     // 32 KB
  unsigned short* hi = (unsigned short*)(ws + (96 << 10));  // 2 MB
  float* out = (float*)d_out;

  prep_kernel<<<256, 256, 0, stream>>>(emb, sq, hi, posk, negk, out);
  mine_mfma_kernel<<<1024, 256, 0, stream>>>(hi, sq, posk, negk);
  triplet_kernel<<<256, 1024, 0, stream>>>(emb, posk, negk, out);
}